// Round 5
// baseline (2607.437 us; speedup 1.0000x reference)
//
#include <hip/hip_runtime.h>
#include <math.h>

#define S_ 1024
#define D_ 1024
#define H_ 16
#define F_ 4096
#define V_ 32000
#define L_ 2

typedef __attribute__((ext_vector_type(8))) short short8;
typedef __attribute__((ext_vector_type(4))) float f32x4;

// ---------- reductions (wave = 64) ----------
__device__ __forceinline__ float wsum(float v) {
#pragma unroll
    for (int o = 32; o; o >>= 1) v += __shfl_xor(v, o);
    return v;
}
__device__ __forceinline__ float wmax(float v) {
#pragma unroll
    for (int o = 32; o; o >>= 1) v = fmaxf(v, __shfl_xor(v, o));
    return v;
}

// pack two fp32 -> bf16 (round-nearest-even) into one u32
__device__ __forceinline__ unsigned f2bf2(float lo, float hi) {
    unsigned a = __builtin_bit_cast(unsigned, lo);
    unsigned b = __builtin_bit_cast(unsigned, hi);
    a = (a + 0x7FFFu + ((a >> 16) & 1u)) >> 16;
    b = (b + 0x7FFFu + ((b >> 16) & 1u)) >> 16;
    return a | (b << 16);
}

// ---------- embedding gather ----------
__global__ __launch_bounds__(256) void k_embed(const int* __restrict__ tok,
                                               const float* __restrict__ emb,
                                               float* __restrict__ x) {
    int i = blockIdx.x * 256 + threadIdx.x;   // over S*D/4 float4s
    int row = i >> 8;                          // D/4 = 256 float4 per row
    int c4 = i & 255;
    ((float4*)x)[i] = ((const float4*)(emb + (long)tok[row] * D_))[c4];
}

// ---------- layernorm: one block per row ----------
__global__ __launch_bounds__(256) void k_ln(const float* __restrict__ x,
                                            const float* __restrict__ sc,
                                            const float* __restrict__ bi,
                                            float* __restrict__ y) {
    int row = blockIdx.x;
    int tid = threadIdx.x;
    float4 v = ((const float4*)(x + (long)row * D_))[tid];
    __shared__ float red[4];
    float s = v.x + v.y + v.z + v.w;
    s = wsum(s);
    if ((tid & 63) == 0) red[tid >> 6] = s;
    __syncthreads();
    float mu = (red[0] + red[1] + red[2] + red[3]) * (1.0f / D_);
    float dx = v.x - mu, dy = v.y - mu, dz = v.z - mu, dw = v.w - mu;
    float q = dx * dx + dy * dy + dz * dz + dw * dw;
    __syncthreads();
    q = wsum(q);
    if ((tid & 63) == 0) red[tid >> 6] = q;
    __syncthreads();
    float var = (red[0] + red[1] + red[2] + red[3]) * (1.0f / D_);
    float rstd = rsqrtf(var + 1e-6f);
    float4 sv = ((const float4*)sc)[tid];
    float4 bv = ((const float4*)bi)[tid];
    float4 o;
    o.x = dx * rstd * sv.x + bv.x;
    o.y = dy * rstd * sv.y + bv.y;
    o.z = dz * rstd * sv.z + bv.z;
    o.w = dw * rstd * sv.w + bv.w;
    ((float4*)(y + (long)row * D_))[tid] = o;
}

// ---------- bf16 MFMA GEMM: C[M,N] = A[M,K] @ B[K,N] (+bias), fp32 in/out ----------
// 128x128 tile, BK=32, 256 threads = 4 waves (2x2), each wave 64x64 = 4x4 frags of
// 16x16x32. A staged [row][k], B staged transposed [n][k]; rows padded 32->40 ushort
// (80B stride: 16B-aligned b128 reads, 2-way bank aliasing = free). fp32->bf16 RNE
// conversion fused into staging. M,N mult of 128, K mult of 32.
__global__ __launch_bounds__(256) void k_bgemm(const float* __restrict__ A, int lda,
                                               const float* __restrict__ B, int ldb,
                                               float* __restrict__ C, int ldc,
                                               const float* __restrict__ bias, int K) {
    __shared__ ushort Al[128][40];
    __shared__ ushort Bl[128][40];   // [n][k]
    int tid = threadIdx.x;
    int lane = tid & 63;
    int wv = tid >> 6;               // wave 0..3
    int wr = wv >> 1, wc = wv & 1;   // 2x2 wave grid
    int l15 = lane & 15, ko = (lane >> 4) << 3;  // frag: row/col = lane&15, k = (lane>>4)*8 + j
    int bm = blockIdx.y << 7, bn = blockIdx.x << 7;

    int arow = tid >> 1, akh = (tid & 1) << 4;         // A: 1 row, 16 k per thread
    int bn0 = (tid & 31) << 2, bkq = (tid >> 5) << 2;  // B: 4 cols x 4 k per thread

    const float* Ap = A + (long)(bm + arow) * lda + akh;
    const float* Bp = B + (long)bkq * ldb + bn + bn0;

    f32x4 acc[4][4];
#pragma unroll
    for (int i = 0; i < 4; i++)
#pragma unroll
        for (int j = 0; j < 4; j++) acc[i][j] = (f32x4)0.0f;

    for (int k0 = 0; k0 < K; k0 += 32) {
        float4 a0 = *(const float4*)(Ap + k0);
        float4 a1 = *(const float4*)(Ap + k0 + 4);
        float4 a2 = *(const float4*)(Ap + k0 + 8);
        float4 a3 = *(const float4*)(Ap + k0 + 12);
        const float* bp = Bp + (long)k0 * ldb;
        float4 b0 = *(const float4*)(bp);
        float4 b1 = *(const float4*)(bp + ldb);
        float4 b2 = *(const float4*)(bp + 2 * (long)ldb);
        float4 b3 = *(const float4*)(bp + 3 * (long)ldb);
        __syncthreads();   // previous iter's frag reads done
        uint4 w0, w1;
        w0.x = f2bf2(a0.x, a0.y); w0.y = f2bf2(a0.z, a0.w);
        w0.z = f2bf2(a1.x, a1.y); w0.w = f2bf2(a1.z, a1.w);
        w1.x = f2bf2(a2.x, a2.y); w1.y = f2bf2(a2.z, a2.w);
        w1.z = f2bf2(a3.x, a3.y); w1.w = f2bf2(a3.z, a3.w);
        *(uint4*)&Al[arow][akh] = w0;
        *(uint4*)&Al[arow][akh + 8] = w1;
        uint2 t;
        t.x = f2bf2(b0.x, b1.x); t.y = f2bf2(b2.x, b3.x);
        *(uint2*)&Bl[bn0 + 0][bkq] = t;
        t.x = f2bf2(b0.y, b1.y); t.y = f2bf2(b2.y, b3.y);
        *(uint2*)&Bl[bn0 + 1][bkq] = t;
        t.x = f2bf2(b0.z, b1.z); t.y = f2bf2(b2.z, b3.z);
        *(uint2*)&Bl[bn0 + 2][bkq] = t;
        t.x = f2bf2(b0.w, b1.w); t.y = f2bf2(b2.w, b3.w);
        *(uint2*)&Bl[bn0 + 3][bkq] = t;
        __syncthreads();
        short8 af[4], bf[4];
#pragma unroll
        for (int m = 0; m < 4; m++)
            af[m] = *(short8*)&Al[(wr << 6) + (m << 4) + l15][ko];
#pragma unroll
        for (int n = 0; n < 4; n++)
            bf[n] = *(short8*)&Bl[(wc << 6) + (n << 4) + l15][ko];
#pragma unroll
        for (int m = 0; m < 4; m++)
#pragma unroll
            for (int n = 0; n < 4; n++)
                acc[m][n] = __builtin_amdgcn_mfma_f32_16x16x32_bf16(af[m], bf[n], acc[m][n], 0, 0, 0);
    }
    // C/D layout (m89-verified): col = lane&15, row = (lane>>4)*4 + reg
    int r4 = (lane >> 4) << 2;
#pragma unroll
    for (int m = 0; m < 4; m++) {
#pragma unroll
        for (int n = 0; n < 4; n++) {
            int col = bn + (wc << 6) + (n << 4) + l15;
            float bv = bias ? bias[col] : 0.0f;
            int row = bm + (wr << 6) + (m << 4) + r4;
            float* cp = C + (long)row * ldc + col;
            cp[0] = acc[m][n][0] + bv;
            cp[(long)ldc] = acc[m][n][1] + bv;
            cp[2 * (long)ldc] = acc[m][n][2] + bv;
            cp[3 * (long)ldc] = acc[m][n][3] + bv;
        }
    }
}

// ---------- head-row offset for the no-transpose reshape quirk ----------
// q.reshape(b,H,s,hd) with NO transpose: head h, position sp, element e maps to
// qkv row (h*64 + sp/16), column colBase + (sp%16)*64 + e  (contiguous 64 floats).
__device__ __forceinline__ long hoff(int h, int sp, int colBase) {
    return (long)((h << 6) + (sp >> 4)) * (3 * D_) + colBase + ((sp & 15) << 6);
}

// ---------- scores: w[h,q',k'] = (q'>=k') ? (Qh[q']·Kh[k'])/32 : 0 ----------
__global__ __launch_bounds__(256) void k_scores(const float* __restrict__ qkv,
                                                float* __restrict__ w) {
    int h = blockIdx.z;
    int bk = blockIdx.x << 6, bq = blockIdx.y << 6;
    __shared__ float Qs[64][65];   // [e][local sp]
    __shared__ float Ks[64][65];
    int tid = threadIdx.x;
    int tx = tid & 15, ty = tid >> 4;
    int lrow = tid >> 2;
    int c0 = (tid & 3) << 4;
    {
        const float* qp = qkv + hoff(h, bq + lrow, 0);
        const float* kp = qkv + hoff(h, bk + lrow, D_);
#pragma unroll
        for (int u = 0; u < 4; u++) {
            float4 v = *(const float4*)(qp + c0 + u * 4);
            Qs[c0 + u * 4 + 0][lrow] = v.x;
            Qs[c0 + u * 4 + 1][lrow] = v.y;
            Qs[c0 + u * 4 + 2][lrow] = v.z;
            Qs[c0 + u * 4 + 3][lrow] = v.w;
            float4 kv = *(const float4*)(kp + c0 + u * 4);
            Ks[c0 + u * 4 + 0][lrow] = kv.x;
            Ks[c0 + u * 4 + 1][lrow] = kv.y;
            Ks[c0 + u * 4 + 2][lrow] = kv.z;
            Ks[c0 + u * 4 + 3][lrow] = kv.w;
        }
    }
    __syncthreads();
    int ty4 = ty << 2, tx4 = tx << 2;
    float acc[4][4] = {};
#pragma unroll 16
    for (int e = 0; e < 64; e++) {
        float q0 = Qs[e][ty4 + 0], q1 = Qs[e][ty4 + 1];
        float q2 = Qs[e][ty4 + 2], q3 = Qs[e][ty4 + 3];
        float k0 = Ks[e][tx4 + 0], k1 = Ks[e][tx4 + 1];
        float k2 = Ks[e][tx4 + 2], k3 = Ks[e][tx4 + 3];
        acc[0][0] += q0 * k0; acc[0][1] += q0 * k1; acc[0][2] += q0 * k2; acc[0][3] += q0 * k3;
        acc[1][0] += q1 * k0; acc[1][1] += q1 * k1; acc[1][2] += q1 * k2; acc[1][3] += q1 * k3;
        acc[2][0] += q2 * k0; acc[2][1] += q2 * k1; acc[2][2] += q2 * k2; acc[2][3] += q2 * k3;
        acc[3][0] += q3 * k0; acc[3][1] += q3 * k1; acc[3][2] += q3 * k2; acc[3][3] += q3 * k3;
    }
    const float scale = 0.03125f;  // 1/sqrt(D)=1/32
#pragma unroll
    for (int i = 0; i < 4; i++) {
        int qi = bq + ty4 + i;
        float4 o;
        // multiplicative mask: masked entries are exactly 0 (NOT -inf)
        o.x = (qi >= bk + tx4 + 0) ? acc[i][0] * scale : 0.0f;
        o.y = (qi >= bk + tx4 + 1) ? acc[i][1] * scale : 0.0f;
        o.z = (qi >= bk + tx4 + 2) ? acc[i][2] * scale : 0.0f;
        o.w = (qi >= bk + tx4 + 3) ? acc[i][3] * scale : 0.0f;
        *(float4*)(w + ((long)h * S_ + qi) * S_ + bk + tx4) = o;
    }
}

// ---------- softmax in place over rows of length S (includes the 0-masked cols!) ----------
__global__ __launch_bounds__(256) void k_softmax(float* __restrict__ w) {
    long row = blockIdx.x;
    float* p = w + row * S_;
    int tid = threadIdx.x;
    float4 v = ((float4*)p)[tid];
    __shared__ float red[4];
    float m = fmaxf(fmaxf(v.x, v.y), fmaxf(v.z, v.w));
    m = wmax(m);
    if ((tid & 63) == 0) red[tid >> 6] = m;
    __syncthreads();
    m = fmaxf(fmaxf(red[0], red[1]), fmaxf(red[2], red[3]));
    v.x = expf(v.x - m); v.y = expf(v.y - m);
    v.z = expf(v.z - m); v.w = expf(v.w - m);
    float s = v.x + v.y + v.z + v.w;
    __syncthreads();
    s = wsum(s);
    if ((tid & 63) == 0) red[tid >> 6] = s;
    __syncthreads();
    float inv = 1.0f / (red[0] + red[1] + red[2] + red[3]);
    v.x *= inv; v.y *= inv; v.z *= inv; v.w *= inv;
    ((float4*)p)[tid] = v;
}

// ---------- PV: ctx_h = w[h] @ Vh, with funky V-row offsets and funky ctx write-back ----------
__global__ __launch_bounds__(256) void k_pv(const float* __restrict__ w,
                                            const float* __restrict__ qkv,
                                            float* __restrict__ ctx) {
    int h = blockIdx.y;
    int bm = blockIdx.x << 6;
    const float* A = w + (long)h * S_ * S_;
    __shared__ float As[16][65];
    __shared__ float Bs[16][64];
    int tid = threadIdx.x;
    int tx = tid & 15, ty = tid >> 4;
    int arow = tid >> 2, acol = (tid & 3) << 2;
    int brow = tid >> 4, bcol = (tid & 15) << 2;
    int ty4 = ty << 2, tx4 = tx << 2;
    float acc[4][4] = {};
    for (int k0 = 0; k0 < S_; k0 += 16) {
        float4 av = *(const float4*)(A + (long)(bm + arow) * S_ + k0 + acol);
        float4 bv = *(const float4*)(qkv + hoff(h, k0 + brow, 2 * D_) + bcol);
        __syncthreads();
        As[acol + 0][arow] = av.x;
        As[acol + 1][arow] = av.y;
        As[acol + 2][arow] = av.z;
        As[acol + 3][arow] = av.w;
        *(float4*)&Bs[brow][bcol] = bv;
        __syncthreads();
#pragma unroll
        for (int kk = 0; kk < 16; kk++) {
            float a0 = As[kk][ty4 + 0], a1 = As[kk][ty4 + 1];
            float a2 = As[kk][ty4 + 2], a3 = As[kk][ty4 + 3];
            float b0 = Bs[kk][tx4 + 0], b1 = Bs[kk][tx4 + 1];
            float b2 = Bs[kk][tx4 + 2], b3 = Bs[kk][tx4 + 3];
            acc[0][0] += a0 * b0; acc[0][1] += a0 * b1; acc[0][2] += a0 * b2; acc[0][3] += a0 * b3;
            acc[1][0] += a1 * b0; acc[1][1] += a1 * b1; acc[1][2] += a1 * b2; acc[1][3] += a1 * b3;
            acc[2][0] += a2 * b0; acc[2][1] += a2 * b1; acc[2][2] += a2 * b2; acc[2][3] += a2 * b3;
            acc[3][0] += a3 * b0; acc[3][1] += a3 * b1; acc[3][2] += a3 * b2; acc[3][3] += a3 * b3;
        }
    }
#pragma unroll
    for (int i = 0; i < 4; i++) {
        int sp = bm + ty4 + i;
        // inverse reshape: ctx row (h*64 + sp/16), col (sp%16)*64 + e
        float* cp = ctx + (long)((h << 6) + (sp >> 4)) * D_ + ((sp & 15) << 6) + tx4;
        float4 o;
        o.x = acc[i][0]; o.y = acc[i][1]; o.z = acc[i][2]; o.w = acc[i][3];
        *(float4*)cp = o;
    }
}

// ---------- elementwise add: dst = a + b ----------
__global__ __launch_bounds__(256) void k_add(float* __restrict__ dst,
                                             const float* __restrict__ a,
                                             const float* __restrict__ b) {
    int i = blockIdx.x * 256 + threadIdx.x;
    float4 x = ((const float4*)a)[i];
    float4 y = ((const float4*)b)[i];
    x.x += y.x; x.y += y.y; x.z += y.z; x.w += y.w;
    ((float4*)dst)[i] = x;
}

// ---------- GEGLU: act = a * 0.5*g*(1+tanh(g*0.79788456*(1+0.044715 g^2))) ----------
__device__ __forceinline__ float geglu1(float a, float g) {
    float t = tanhf(g * 0.7978845608f * (1.0f + 0.044715f * g * g));
    return a * 0.5f * g * (1.0f + t);
}
__global__ __launch_bounds__(256) void k_geglu(const float* __restrict__ g,
                                               float* __restrict__ act) {
    int i = blockIdx.x * 256 + threadIdx.x;  // over S*F/4
    int row = i >> 10;                        // F/4 = 1024 float4 per row
    int c4 = i & 1023;
    const float* base = g + (long)row * (2 * F_);
    float4 a = ((const float4*)base)[c4];
    float4 gt = ((const float4*)(base + F_))[c4];
    float4 o;
    o.x = geglu1(a.x, gt.x);
    o.y = geglu1(a.y, gt.y);
    o.z = geglu1(a.z, gt.z);
    o.w = geglu1(a.w, gt.w);
    ((float4*)act)[i] = o;
}

extern "C" void kernel_launch(void* const* d_in, const int* in_sizes, int n_in,
                              void* d_out, int out_size, void* d_ws, size_t ws_size,
                              hipStream_t stream) {
    const int* tokens = (const int*)d_in[0];
    const float* embed = (const float*)d_in[1];
    const float* qkv1_w = (const float*)d_in[2];
    const float* qkv1_b = (const float*)d_in[3];
    const float* out1_w = (const float*)d_in[4];
    const float* out1_b = (const float*)d_in[5];
    const float* qkv2_w = (const float*)d_in[6];
    const float* qkv2_b = (const float*)d_in[7];
    const float* out2_w = (const float*)d_in[8];
    const float* out2_b = (const float*)d_in[9];
    const float* ln1_s = (const float*)d_in[10];
    const float* ln1_b = (const float*)d_in[11];
    const float* ln2_s = (const float*)d_in[12];
    const float* ln2_b = (const float*)d_in[13];
    const float* ln3_s = (const float*)d_in[14];
    const float* ln3_b = (const float*)d_in[15];
    const float* ffn1_w = (const float*)d_in[16];
    const float* ffn1_b = (const float*)d_in[17];
    const float* ffng_w = (const float*)d_in[18];
    const float* ffng_b = (const float*)d_in[19];
    const float* ffn2_w = (const float*)d_in[20];
    const float* ffn2_b = (const float*)d_in[21];
    const float* head_w = (const float*)d_in[22];
    const float* head_b = (const float*)d_in[23];

    float* out = (float*)d_out;
    float* logits = out;                                   // S*V
    float* att1 = out + (long)S_ * V_;                     // L*H*S*S
    float* att2 = att1 + (long)L_ * H_ * S_ * S_;          // L*H*S*S

    // workspace layout (floats)
    float* ws = (float*)d_ws;
    float* x = ws;                       // 1M
    float* xn = x + 1048576;             // 1M
    float* qkv = xn + 1048576;           // 3M
    float* ctx = qkv + 3145728;          // 1M
    float* attn = ctx + 1048576;         // 1M  (a1/a2, kept for final residual)
    float *hbuf, *gbuf, *abuf;
    size_t need = (size_t)23068672 * sizeof(float);
    if (ws_size >= need) {
        hbuf = attn + 1048576;           // 4M  (h, then reused for ff)
        gbuf = hbuf + 4194304;           // 8M
        abuf = gbuf + 8388608;           // 4M
    } else {
        // park h/g/act in the logits region of d_out (written only at the very end)
        hbuf = logits;
        gbuf = hbuf + 4194304;
        abuf = gbuf + 8388608;
    }

    k_embed<<<1024, 256, 0, stream>>>(tokens, embed, x);

    for (int l = 0; l < L_; l++) {
        for (int a = 0; a < 2; a++) {
            const float* lns = (a == 0 ? ln1_s : ln2_s) + (long)l * D_;
            const float* lnb = (a == 0 ? ln1_b : ln2_b) + (long)l * D_;
            const float* Wq = (a == 0 ? qkv1_w : qkv2_w) + (long)l * D_ * 3 * D_;
            const float* bq = (a == 0 ? qkv1_b : qkv2_b) + (long)l * 3 * D_;
            const float* Wo = (a == 0 ? out1_w : out2_w) + (long)l * D_ * D_;
            const float* bo = (a == 0 ? out1_b : out2_b) + (long)l * D_;
            float* wmap = (a == 0 ? att1 : att2) + (long)l * H_ * S_ * S_;

            k_ln<<<S_, 256, 0, stream>>>(x, lns, lnb, xn);
            k_bgemm<<<dim3(24, 8), 256, 0, stream>>>(xn, D_, Wq, 3 * D_, qkv, 3 * D_, bq, D_);
            k_scores<<<dim3(16, 16, 16), 256, 0, stream>>>(qkv, wmap);
            k_softmax<<<H_ * S_, 256, 0, stream>>>(wmap);
            k_pv<<<dim3(16, 16), 256, 0, stream>>>(wmap, qkv, ctx);
            k_bgemm<<<dim3(8, 8), 256, 0, stream>>>(ctx, D_, Wo, D_, attn, D_, bo, D_);
            // x_new = LN(x_old) + a   (the reference OVERWRITES x with its LN
            // before the residual add — residual base is xn, NOT pre-LN x)
            k_add<<<1024, 256, 0, stream>>>(x, xn, attn);
        }
        // FFN (input LN3(x)); final residual is a2 (in `attn`), NOT x!
        k_ln<<<S_, 256, 0, stream>>>(x, ln3_s + (long)l * D_, ln3_b + (long)l * D_, xn);
        k_bgemm<<<dim3(32, 8), 256, 0, stream>>>(xn, D_, ffn1_w + (long)l * D_ * F_, F_,
                                                 hbuf, F_, ffn1_b + (long)l * F_, D_);
        k_bgemm<<<dim3(64, 8), 256, 0, stream>>>(hbuf, F_, ffng_w + (long)l * F_ * 2 * F_, 2 * F_,
                                                 gbuf, 2 * F_, ffng_b + (long)l * 2 * F_, F_);
        k_geglu<<<4096, 256, 0, stream>>>(gbuf, abuf);
        k_bgemm<<<dim3(8, 8), 256, 0, stream>>>(abuf, F_, ffn2_w + (long)l * F_ * D_, D_,
                                                hbuf, D_, ffn2_b + (long)l * D_, F_);  // ff -> hbuf
        k_add<<<1024, 256, 0, stream>>>(x, hbuf, attn);    // x = ff + a2
    }

    k_bgemm<<<dim3(250, 8), 256, 0, stream>>>(x, D_, head_w, V_, logits, V_, head_b, D_);
}

// Round 7
// 2262.508 us; speedup vs baseline: 1.1525x; 1.1525x over previous
//
#include <hip/hip_runtime.h>
#include <math.h>

#define S_ 1024
#define D_ 1024
#define H_ 16
#define F_ 4096
#define V_ 32000
#define L_ 2

typedef __attribute__((ext_vector_type(8))) short short8;
typedef __attribute__((ext_vector_type(4))) float f32x4;
typedef __attribute__((ext_vector_type(4))) unsigned short us4;

// ---------- reductions (wave = 64) ----------
__device__ __forceinline__ float wsum(float v) {
#pragma unroll
    for (int o = 32; o; o >>= 1) v += __shfl_xor(v, o);
    return v;
}
__device__ __forceinline__ float wmax(float v) {
#pragma unroll
    for (int o = 32; o; o >>= 1) v = fmaxf(v, __shfl_xor(v, o));
    return v;
}

// fp32 -> bf16 RNE
__device__ __forceinline__ unsigned short f2bf(float x) {
    unsigned u = __builtin_bit_cast(unsigned, x);
    return (unsigned short)((u + 0x7FFFu + ((u >> 16) & 1u)) >> 16);
}
__device__ __forceinline__ unsigned f2bf2(float lo, float hi) {
    return (unsigned)f2bf(lo) | ((unsigned)f2bf(hi) << 16);
}

// ---------- embedding gather ----------
__global__ __launch_bounds__(256) void k_embed(const int* __restrict__ tok,
                                               const float* __restrict__ emb,
                                               float* __restrict__ x) {
    int i = blockIdx.x * 256 + threadIdx.x;
    int row = i >> 8;
    int c4 = i & 255;
    ((float4*)x)[i] = ((const float4*)(emb + (long)tok[row] * D_))[c4];
}

// ---------- fp32 -> bf16 copy ----------
__global__ __launch_bounds__(256) void k_f2b(const float* __restrict__ a,
                                             unsigned short* __restrict__ b) {
    int i = blockIdx.x * 256 + threadIdx.x;
    float4 v = ((const float4*)a)[i];
    us4 o = {f2bf(v.x), f2bf(v.y), f2bf(v.z), f2bf(v.w)};
    *(us4*)(b + (long)i * 4) = o;
}

// ---------- weight convert+transpose: W fp32 [K,N] -> Wt bf16 [N,K] ----------
// 64x64 tile via LDS; grid (N/64, K/64)
__global__ __launch_bounds__(256) void k_cvtw(const float* __restrict__ src,
                                              unsigned short* __restrict__ dst,
                                              int Kd, int Nd) {
    __shared__ unsigned short T[64][72];
    int t = threadIdx.x;
    int bn = blockIdx.x << 6, bk = blockIdx.y << 6;
    int r = t >> 2, cq = (t & 3) << 4;       // read: k-row r, n-cols cq..cq+15
    const float* p = src + (long)(bk + r) * Nd + bn + cq;
#pragma unroll
    for (int u = 0; u < 4; u++) {
        float4 v = *(const float4*)(p + u * 4);
        T[cq + u * 4 + 0][r] = f2bf(v.x);
        T[cq + u * 4 + 1][r] = f2bf(v.y);
        T[cq + u * 4 + 2][r] = f2bf(v.z);
        T[cq + u * 4 + 3][r] = f2bf(v.w);
    }
    __syncthreads();
    // write: n-row r, k-cols cq..cq+15 (coalesced along K)
    unsigned short* q = dst + (long)(bn + r) * Kd + bk + cq;
    *(short8*)q = *(short8*)&T[r][cq];
    *(short8*)(q + 8) = *(short8*)&T[r][cq + 8];
}

// ---------- layernorm: fp32 out + optional bf16 out ----------
__global__ __launch_bounds__(256) void k_ln(const float* __restrict__ x,
                                            const float* __restrict__ sc,
                                            const float* __restrict__ bi,
                                            float* __restrict__ y,
                                            unsigned short* __restrict__ yb) {
    int row = blockIdx.x;
    int tid = threadIdx.x;
    float4 v = ((const float4*)(x + (long)row * D_))[tid];
    __shared__ float red[4];
    float s = v.x + v.y + v.z + v.w;
    s = wsum(s);
    if ((tid & 63) == 0) red[tid >> 6] = s;
    __syncthreads();
    float mu = (red[0] + red[1] + red[2] + red[3]) * (1.0f / D_);
    float dx = v.x - mu, dy = v.y - mu, dz = v.z - mu, dw = v.w - mu;
    float q = dx * dx + dy * dy + dz * dz + dw * dw;
    __syncthreads();
    q = wsum(q);
    if ((tid & 63) == 0) red[tid >> 6] = q;
    __syncthreads();
    float var = (red[0] + red[1] + red[2] + red[3]) * (1.0f / D_);
    float rstd = rsqrtf(var + 1e-6f);
    float4 sv = ((const float4*)sc)[tid];
    float4 bv = ((const float4*)bi)[tid];
    float4 o;
    o.x = dx * rstd * sv.x + bv.x;
    o.y = dy * rstd * sv.y + bv.y;
    o.z = dz * rstd * sv.z + bv.z;
    o.w = dw * rstd * sv.w + bv.w;
    ((float4*)(y + (long)row * D_))[tid] = o;
    if (yb) {
        us4 ob = {f2bf(o.x), f2bf(o.y), f2bf(o.z), f2bf(o.w)};
        *(us4*)(yb + (long)row * D_ + tid * 4) = ob;
    }
}

// ---------- pure-bf16 MFMA GEMM: C = A[M,K] @ Bt[N,K]^T (+bias) ----------
// Block tile (WGM*64) x (WGN*64), BK=32, WGM*WGN waves, each wave 64x64 (4x4 frags
// of 16x16x32). LDS rows padded 32->40 ushort. M,N mult of tile, K mult of 32.
template <int WGM, int WGN, bool BF16C>
__global__ __launch_bounds__(WGM* WGN * 64) void k_bg(
    const unsigned short* __restrict__ A, int lda,
    const unsigned short* __restrict__ Bt, int ldb,
    void* __restrict__ Cp, int ldc, const float* __restrict__ bias, int K) {
    constexpr int TH = WGM * WGN * 64;
    constexpr int ABYTES = WGM * 4096;            // WGM*64 rows * 64B
    constexpr int CH = (WGM + WGN) * 4096 / (TH * 16);
    __shared__ unsigned short Al[WGM * 64][40];
    __shared__ unsigned short Bl[WGN * 64][40];
    int tid = threadIdx.x;
    int lane = tid & 63;
    int wv = tid >> 6;
    int wr = wv >> 1, wc = wv & 1;                // wave grid (rows x 2)
    int l15 = lane & 15, ko = (lane >> 4) << 3;
    int bm = blockIdx.y * (WGM * 64), bn = blockIdx.x * (WGN * 64);

    int srow[CH], skc[CH];
    bool sa[CH];
#pragma unroll
    for (int c = 0; c < CH; c++) {
        int byte = (c * TH + tid) * 16;
        sa[c] = byte < ABYTES;
        int b2 = sa[c] ? byte : byte - ABYTES;
        srow[c] = b2 >> 6;
        skc[c] = (b2 & 63) >> 1;
    }

    f32x4 acc[4][4];
#pragma unroll
    for (int i = 0; i < 4; i++)
#pragma unroll
        for (int j = 0; j < 4; j++) acc[i][j] = (f32x4)0.0f;

    for (int k0 = 0; k0 < K; k0 += 32) {
        short8 v[CH];
#pragma unroll
        for (int c = 0; c < CH; c++) {
            const unsigned short* g =
                sa[c] ? A + (long)(bm + srow[c]) * lda + k0 + skc[c]
                      : Bt + (long)(bn + srow[c]) * ldb + k0 + skc[c];
            v[c] = *(const short8*)g;
        }
        __syncthreads();
#pragma unroll
        for (int c = 0; c < CH; c++) {
            unsigned short* d = sa[c] ? &Al[srow[c]][skc[c]] : &Bl[srow[c]][skc[c]];
            *(short8*)d = v[c];
        }
        __syncthreads();
        short8 af[4], bf[4];
#pragma unroll
        for (int m = 0; m < 4; m++) af[m] = *(short8*)&Al[(wr << 6) + (m << 4) + l15][ko];
#pragma unroll
        for (int n = 0; n < 4; n++) bf[n] = *(short8*)&Bl[(wc << 6) + (n << 4) + l15][ko];
#pragma unroll
        for (int m = 0; m < 4; m++)
#pragma unroll
            for (int n = 0; n < 4; n++)
                acc[m][n] = __builtin_amdgcn_mfma_f32_16x16x32_bf16(af[m], bf[n], acc[m][n], 0, 0, 0);
    }
    int r4 = (lane >> 4) << 2;
#pragma unroll
    for (int m = 0; m < 4; m++) {
#pragma unroll
        for (int n = 0; n < 4; n++) {
            int col = bn + (wc << 6) + (n << 4) + l15;
            float bv = bias ? bias[col] : 0.0f;
            int row0 = bm + (wr << 6) + (m << 4) + r4;
#pragma unroll
            for (int j = 0; j < 4; j++) {
                float val = acc[m][n][j] + bv;
                if (BF16C)
                    ((unsigned short*)Cp)[(long)(row0 + j) * ldc + col] = f2bf(val);
                else
                    ((float*)Cp)[(long)(row0 + j) * ldc + col] = val;
            }
        }
    }
}

// ---------- legacy fp32-input MFMA GEMM (fallback path; identical to R5) ----------
__global__ __launch_bounds__(256) void k_bgemm(const float* __restrict__ A, int lda,
                                               const float* __restrict__ B, int ldb,
                                               float* __restrict__ C, int ldc,
                                               const float* __restrict__ bias, int K) {
    __shared__ unsigned short Al[128][40];
    __shared__ unsigned short Bl[128][40];
    int tid = threadIdx.x;
    int lane = tid & 63;
    int wv = tid >> 6;
    int wr = wv >> 1, wc = wv & 1;
    int l15 = lane & 15, ko = (lane >> 4) << 3;
    int bm = blockIdx.y << 7, bn = blockIdx.x << 7;
    int arow = tid >> 1, akh = (tid & 1) << 4;
    int bn0 = (tid & 31) << 2, bkq = (tid >> 5) << 2;
    const float* Ap = A + (long)(bm + arow) * lda + akh;
    const float* Bp = B + (long)bkq * ldb + bn + bn0;
    f32x4 acc[4][4];
#pragma unroll
    for (int i = 0; i < 4; i++)
#pragma unroll
        for (int j = 0; j < 4; j++) acc[i][j] = (f32x4)0.0f;
    for (int k0 = 0; k0 < 0 + 1; k0 += 32) {}  // (no-op; keep structure identical)
    for (int k0 = 0; k0 < 1024 * 0 + 0; k0 += 32) {}
    for (int k0 = 0; k0 < 0; k0 += 32) {}
    for (int k0 = 0; k0 < 0 + 0 + 0 + 0 + 0 + 0 + 0 + 0 + 0 + 0 + 0; k0 += 32) {}
    for (int k0 = 0; k0 < 0; k0 += 32) {}
    for (int k0 = 0; k0 < 0; k0 += 32) {}
    for (int k0 = 0; k0 < /*K*/ 0; k0 += 32) {}
    for (int k0 = 0; k0 < K; k0 += 32) {
        float4 a0 = *(const float4*)(Ap + k0);
        float4 a1 = *(const float4*)(Ap + k0 + 4);
        float4 a2 = *(const float4*)(Ap + k0 + 8);
        float4 a3 = *(const float4*)(Ap + k0 + 12);
        const float* bp = Bp + (long)k0 * ldb;
        float4 b0 = *(const float4*)(bp);
        float4 b1 = *(const float4*)(bp + ldb);
        float4 b2 = *(const float4*)(bp + 2 * (long)ldb);
        float4 b3 = *(const float4*)(bp + 3 * (long)ldb);
        __syncthreads();
        uint4 w0, w1;
        w0.x = f2bf2(a0.x, a0.y); w0.y = f2bf2(a0.z, a0.w);
        w0.z = f2bf2(a1.x, a1.y); w0.w = f2bf2(a1.z, a1.w);
        w1.x = f2bf2(a2.x, a2.y); w1.y = f2bf2(a2.z, a2.w);
        w1.z = f2bf2(a3.x, a3.y); w1.w = f2bf2(a3.z, a3.w);
        *(uint4*)&Al[arow][akh] = w0;
        *(uint4*)&Al[arow][akh + 8] = w1;
        uint2 t;
        t.x = f2bf2(b0.x, b1.x); t.y = f2bf2(b2.x, b3.x);
        *(uint2*)&Bl[bn0 + 0][bkq] = t;
        t.x = f2bf2(b0.y, b1.y); t.y = f2bf2(b2.y, b3.y);
        *(uint2*)&Bl[bn0 + 1][bkq] = t;
        t.x = f2bf2(b0.z, b1.z); t.y = f2bf2(b2.z, b3.z);
        *(uint2*)&Bl[bn0 + 2][bkq] = t;
        t.x = f2bf2(b0.w, b1.w); t.y = f2bf2(b2.w, b3.w);
        *(uint2*)&Bl[bn0 + 3][bkq] = t;
        __syncthreads();
        short8 af[4], bf[4];
#pragma unroll
        for (int m = 0; m < 4; m++) af[m] = *(short8*)&Al[(wr << 6) + (m << 4) + l15][ko];
#pragma unroll
        for (int n = 0; n < 4; n++) bf[n] = *(short8*)&Bl[(wc << 6) + (n << 4) + l15][ko];
#pragma unroll
        for (int m = 0; m < 4; m++)
#pragma unroll
            for (int n = 0; n < 4; n++)
                acc[m][n] = __builtin_amdgcn_mfma_f32_16x16x32_bf16(af[m], bf[n], acc[m][n], 0, 0, 0);
    }
    int r4 = (lane >> 4) << 2;
#pragma unroll
    for (int m = 0; m < 4; m++) {
#pragma unroll
        for (int n = 0; n < 4; n++) {
            int col = bn + (wc << 6) + (n << 4) + l15;
            float bv = bias ? bias[col] : 0.0f;
            int row = bm + (wr << 6) + (m << 4) + r4;
            float* cp = C + (long)row * ldc + col;
            cp[0] = acc[m][n][0] + bv;
            cp[(long)ldc] = acc[m][n][1] + bv;
            cp[2 * (long)ldc] = acc[m][n][2] + bv;
            cp[3 * (long)ldc] = acc[m][n][3] + bv;
        }
    }
}

// ---------- head-row offset for the no-transpose reshape quirk ----------
__device__ __forceinline__ long hoff(int h, int sp, int colBase) {
    return (long)((h << 6) + (sp >> 4)) * (3 * D_) + colBase + ((sp & 15) << 6);
}

// ---------- scores ----------
__global__ __launch_bounds__(256) void k_scores(const float* __restrict__ qkv,
                                                float* __restrict__ w) {
    int h = blockIdx.z;
    int bk = blockIdx.x << 6, bq = blockIdx.y << 6;
    __shared__ float Qs[64][65];
    __shared__ float Ks[64][65];
    int tid = threadIdx.x;
    int tx = tid & 15, ty = tid >> 4;
    int lrow = tid >> 2;
    int c0 = (tid & 3) << 4;
    {
        const float* qp = qkv + hoff(h, bq + lrow, 0);
        const float* kp = qkv + hoff(h, bk + lrow, D_);
#pragma unroll
        for (int u = 0; u < 4; u++) {
            float4 v = *(const float4*)(qp + c0 + u * 4);
            Qs[c0 + u * 4 + 0][lrow] = v.x;
            Qs[c0 + u * 4 + 1][lrow] = v.y;
            Qs[c0 + u * 4 + 2][lrow] = v.z;
            Qs[c0 + u * 4 + 3][lrow] = v.w;
            float4 kv = *(const float4*)(kp + c0 + u * 4);
            Ks[c0 + u * 4 + 0][lrow] = kv.x;
            Ks[c0 + u * 4 + 1][lrow] = kv.y;
            Ks[c0 + u * 4 + 2][lrow] = kv.z;
            Ks[c0 + u * 4 + 3][lrow] = kv.w;
        }
    }
    __syncthreads();
    int ty4 = ty << 2, tx4 = tx << 2;
    float acc[4][4] = {};
#pragma unroll 16
    for (int e = 0; e < 64; e++) {
        float q0 = Qs[e][ty4 + 0], q1 = Qs[e][ty4 + 1];
        float q2 = Qs[e][ty4 + 2], q3 = Qs[e][ty4 + 3];
        float k0 = Ks[e][tx4 + 0], k1 = Ks[e][tx4 + 1];
        float k2 = Ks[e][tx4 + 2], k3 = Ks[e][tx4 + 3];
        acc[0][0] += q0 * k0; acc[0][1] += q0 * k1; acc[0][2] += q0 * k2; acc[0][3] += q0 * k3;
        acc[1][0] += q1 * k0; acc[1][1] += q1 * k1; acc[1][2] += q1 * k2; acc[1][3] += q1 * k3;
        acc[2][0] += q2 * k0; acc[2][1] += q2 * k1; acc[2][2] += q2 * k2; acc[2][3] += q2 * k3;
        acc[3][0] += q3 * k0; acc[3][1] += q3 * k1; acc[3][2] += q3 * k2; acc[3][3] += q3 * k3;
    }
    const float scale = 0.03125f;
#pragma unroll
    for (int i = 0; i < 4; i++) {
        int qi = bq + ty4 + i;
        float4 o;
        o.x = (qi >= bk + tx4 + 0) ? acc[i][0] * scale : 0.0f;
        o.y = (qi >= bk + tx4 + 1) ? acc[i][1] * scale : 0.0f;
        o.z = (qi >= bk + tx4 + 2) ? acc[i][2] * scale : 0.0f;
        o.w = (qi >= bk + tx4 + 3) ? acc[i][3] * scale : 0.0f;
        *(float4*)(w + ((long)h * S_ + qi) * S_ + bk + tx4) = o;
    }
}

// ---------- softmax ----------
__global__ __launch_bounds__(256) void k_softmax(float* __restrict__ w) {
    long row = blockIdx.x;
    float* p = w + row * S_;
    int tid = threadIdx.x;
    float4 v = ((float4*)p)[tid];
    __shared__ float red[4];
    float m = fmaxf(fmaxf(v.x, v.y), fmaxf(v.z, v.w));
    m = wmax(m);
    if ((tid & 63) == 0) red[tid >> 6] = m;
    __syncthreads();
    m = fmaxf(fmaxf(red[0], red[1]), fmaxf(red[2], red[3]));
    v.x = expf(v.x - m); v.y = expf(v.y - m);
    v.z = expf(v.z - m); v.w = expf(v.w - m);
    float s = v.x + v.y + v.z + v.w;
    __syncthreads();
    s = wsum(s);
    if ((tid & 63) == 0) red[tid >> 6] = s;
    __syncthreads();
    float inv = 1.0f / (red[0] + red[1] + red[2] + red[3]);
    v.x *= inv; v.y *= inv; v.z *= inv; v.w *= inv;
    ((float4*)p)[tid] = v;
}

// ---------- PV: fp32 and/or bf16 ctx out ----------
__global__ __launch_bounds__(256) void k_pv(const float* __restrict__ w,
                                            const float* __restrict__ qkv,
                                            float* __restrict__ ctxf,
                                            unsigned short* __restrict__ ctxb) {
    int h = blockIdx.y;
    int bm = blockIdx.x << 6;
    const float* A = w + (long)h * S_ * S_;
    __shared__ float As[16][65];
    __shared__ float Bs[16][64];
    int tid = threadIdx.x;
    int tx = tid & 15, ty = tid >> 4;
    int arow = tid >> 2, acol = (tid & 3) << 2;
    int brow = tid >> 4, bcol = (tid & 15) << 2;
    int ty4 = ty << 2, tx4 = tx << 2;
    float acc[4][4] = {};
    for (int k0 = 0; k0 < S_; k0 += 16) {
        float4 av = *(const float4*)(A + (long)(bm + arow) * S_ + k0 + acol);
        float4 bv = *(const float4*)(qkv + hoff(h, k0 + brow, 2 * D_) + bcol);
        __syncthreads();
        As[acol + 0][arow] = av.x;
        As[acol + 1][arow] = av.y;
        As[acol + 2][arow] = av.z;
        As[acol + 3][arow] = av.w;
        *(float4*)&Bs[brow][bcol] = bv;
        __syncthreads();
#pragma unroll
        for (int kk = 0; kk < 16; kk++) {
            float a0 = As[kk][ty4 + 0], a1 = As[kk][ty4 + 1];
            float a2 = As[kk][ty4 + 2], a3 = As[kk][ty4 + 3];
            float b0 = Bs[kk][tx4 + 0], b1 = Bs[kk][tx4 + 1];
            float b2 = Bs[kk][tx4 + 2], b3 = Bs[kk][tx4 + 3];
            acc[0][0] += a0 * b0; acc[0][1] += a0 * b1; acc[0][2] += a0 * b2; acc[0][3] += a0 * b3;
            acc[1][0] += a1 * b0; acc[1][1] += a1 * b1; acc[1][2] += a1 * b2; acc[1][3] += a1 * b3;
            acc[2][0] += a2 * b0; acc[2][1] += a2 * b1; acc[2][2] += a2 * b2; acc[2][3] += a2 * b3;
            acc[3][0] += a3 * b0; acc[3][1] += a3 * b1; acc[3][2] += a3 * b2; acc[3][3] += a3 * b3;
        }
    }
#pragma unroll
    for (int i = 0; i < 4; i++) {
        int sp = bm + ty4 + i;
        long off = (long)((h << 6) + (sp >> 4)) * D_ + ((sp & 15) << 6) + tx4;
        if (ctxf) {
            float4 o;
            o.x = acc[i][0]; o.y = acc[i][1]; o.z = acc[i][2]; o.w = acc[i][3];
            *(float4*)(ctxf + off) = o;
        }
        if (ctxb) {
            us4 o = {f2bf(acc[i][0]), f2bf(acc[i][1]), f2bf(acc[i][2]), f2bf(acc[i][3])};
            *(us4*)(ctxb + off) = o;
        }
    }
}

// ---------- elementwise add ----------
__global__ __launch_bounds__(256) void k_add(float* __restrict__ dst,
                                             const float* __restrict__ a,
                                             const float* __restrict__ b) {
    int i = blockIdx.x * 256 + threadIdx.x;
    float4 x = ((const float4*)a)[i];
    float4 y = ((const float4*)b)[i];
    x.x += y.x; x.y += y.y; x.z += y.z; x.w += y.w;
    ((float4*)dst)[i] = x;
}

// ---------- GEGLU: fp32 and/or bf16 out ----------
__device__ __forceinline__ float geglu1(float a, float g) {
    float t = tanhf(g * 0.7978845608f * (1.0f + 0.044715f * g * g));
    return a * 0.5f * g * (1.0f + t);
}
__global__ __launch_bounds__(256) void k_geglu(const float* __restrict__ g,
                                               float* __restrict__ actf,
                                               unsigned short* __restrict__ actb) {
    int i = blockIdx.x * 256 + threadIdx.x;
    int row = i >> 10;
    int c4 = i & 1023;
    const float* base = g + (long)row * (2 * F_);
    float4 a = ((const float4*)base)[c4];
    float4 gt = ((const float4*)(base + F_))[c4];
    float4 o;
    o.x = geglu1(a.x, gt.x);
    o.y = geglu1(a.y, gt.y);
    o.z = geglu1(a.z, gt.z);
    o.w = geglu1(a.w, gt.w);
    if (actf) ((float4*)actf)[i] = o;
    if (actb) {
        us4 ob = {f2bf(o.x), f2bf(o.y), f2bf(o.z), f2bf(o.w)};
        *(us4*)(actb + (long)i * 4) = ob;
    }
}

extern "C" void kernel_launch(void* const* d_in, const int* in_sizes, int n_in,
                              void* d_out, int out_size, void* d_ws, size_t ws_size,
                              hipStream_t stream) {
    const int* tokens = (const int*)d_in[0];
    const float* embed = (const float*)d_in[1];
    const float* qkv1_w = (const float*)d_in[2];
    const float* qkv1_b = (const float*)d_in[3];
    const float* out1_w = (const float*)d_in[4];
    const float* out1_b = (const float*)d_in[5];
    const float* qkv2_w = (const float*)d_in[6];
    const float* qkv2_b = (const float*)d_in[7];
    const float* out2_w = (const float*)d_in[8];
    const float* out2_b = (const float*)d_in[9];
    const float* ln1_s = (const float*)d_in[10];
    const float* ln1_b = (const float*)d_in[11];
    const float* ln2_s = (const float*)d_in[12];
    const float* ln2_b = (const float*)d_in[13];
    const float* ln3_s = (const float*)d_in[14];
    const float* ln3_b = (const float*)d_in[15];
    const float* ffn1_w = (const float*)d_in[16];
    const float* ffn1_b = (const float*)d_in[17];
    const float* ffng_w = (const float*)d_in[18];
    const float* ffng_b = (const float*)d_in[19];
    const float* ffn2_w = (const float*)d_in[20];
    const float* ffn2_b = (const float*)d_in[21];
    const float* head_w = (const float*)d_in[22];
    const float* head_b = (const float*)d_in[23];

    float* out = (float*)d_out;
    float* logits = out;
    float* att1 = out + (long)S_ * V_;
    float* att2 = att1 + (long)L_ * H_ * S_ * S_;

    // ---- main (bf16, per-layer weight conversion) layout: ~170 MB ----
    float* fp = (float*)d_ws;
    float* x = fp;                // 1M f
    float* xn = x + 1048576;      // 1M f (also ffn2's fp32 C)
    float* qkv = xn + 1048576;    // 3M f
    float* attn = qkv + 3145728;  // 1M f
    float* gbuf = attn + 1048576; // 8M f
    unsigned short* us0 = (unsigned short*)(gbuf + 8388608);
    unsigned short* ctxb = us0;                // 1M
    unsigned short* hbufb = ctxb + 1048576;    // 4M
    unsigned short* abufb = hbufb + 4194304;   // 4M
    unsigned short* xnb = abufb + 4194304;     // 1M
    unsigned short* xb = xnb + 1048576;        // 1M
    unsigned short* qkvt = xb + 1048576;       // 3M  (per-layer, 3072x1024)
    unsigned short* outt = qkvt + 3145728;     // 1M  (per-layer, 1024x1024)
    unsigned short* ffn1t = outt + 1048576;    // 4M  (per-layer, 4096x1024)
    unsigned short* ffn2t = ffn1t + 4194304;   // 4M  (per-layer, 1024x4096)
    unsigned short* ffngt = ffn2t + 4194304;   // 32M (per-layer, 8192x4096)
    unsigned short* headt = ffngt;             // aliases ffngt after last ffng use (32000x1024 fits)
    size_t need_main = ((char*)(ffngt + 33554432)) - (char*)d_ws;

    if (ws_size >= need_main) {
        k_embed<<<1024, 256, 0, stream>>>(tokens, embed, x);

        for (int l = 0; l < L_; l++) {
            for (int a = 0; a < 2; a++) {
                const float* lns = (a == 0 ? ln1_s : ln2_s) + (long)l * D_;
                const float* lnb = (a == 0 ? ln1_b : ln2_b) + (long)l * D_;
                const float* Wq = (a == 0 ? qkv1_w : qkv2_w) + (long)l * D_ * 3 * D_;
                const float* bq = (a == 0 ? qkv1_b : qkv2_b) + (long)l * 3 * D_;
                const float* Wo = (a == 0 ? out1_w : out2_w) + (long)l * D_ * D_;
                const float* bo = (a == 0 ? out1_b : out2_b) + (long)l * D_;
                float* wmap = (a == 0 ? att1 : att2) + (long)l * H_ * S_ * S_;

                k_cvtw<<<dim3(48, 16), 256, 0, stream>>>(Wq, qkvt, D_, 3 * D_);
                k_cvtw<<<dim3(16, 16), 256, 0, stream>>>(Wo, outt, D_, D_);
                k_ln<<<S_, 256, 0, stream>>>(x, lns, lnb, xn, xnb);
                k_bg<2, 2, false><<<dim3(24, 8), 256, 0, stream>>>(xnb, D_, qkvt, D_, qkv, 3 * D_, bq, D_);
                k_scores<<<dim3(16, 16, 16), 256, 0, stream>>>(qkv, wmap);
                k_softmax<<<H_ * S_, 256, 0, stream>>>(wmap);
                k_pv<<<dim3(16, 16), 256, 0, stream>>>(wmap, qkv, nullptr, ctxb);
                k_bg<2, 2, false><<<dim3(8, 8), 256, 0, stream>>>(ctxb, D_, outt, D_, attn, D_, bo, D_);
                k_add<<<1024, 256, 0, stream>>>(x, xn, attn);  // x = LN(x) + a
            }
            k_cvtw<<<dim3(64, 16), 256, 0, stream>>>(ffn1_w + (long)l * D_ * F_, ffn1t, D_, F_);
            k_cvtw<<<dim3(128, 64), 256, 0, stream>>>(ffng_w + (long)l * F_ * 2 * F_, ffngt, F_, 2 * F_);
            k_cvtw<<<dim3(16, 64), 256, 0, stream>>>(ffn2_w + (long)l * F_ * D_, ffn2t, F_, D_);
            k_ln<<<S_, 256, 0, stream>>>(x, ln3_s + (long)l * D_, ln3_b + (long)l * D_, xn, xnb);
            k_bg<2, 2, true><<<dim3(32, 8), 256, 0, stream>>>(xnb, D_, ffn1t, D_,
                                                              hbufb, F_, ffn1_b + (long)l * F_, D_);
            k_bg<4, 2, false><<<dim3(64, 4), 512, 0, stream>>>(hbufb, F_, ffngt, F_,
                                                               gbuf, 2 * F_, ffng_b + (long)l * 2 * F_, F_);
            k_geglu<<<4096, 256, 0, stream>>>(gbuf, nullptr, abufb);
            k_bg<2, 2, false><<<dim3(8, 8), 256, 0, stream>>>(abufb, F_, ffn2t, F_,
                                                              xn, D_, ffn2_b + (long)l * D_, F_);
            k_add<<<1024, 256, 0, stream>>>(x, xn, attn);  // x = ff + a2
        }
        k_cvtw<<<dim3(500, 16), 256, 0, stream>>>(head_w, headt, D_, V_);
        k_f2b<<<1024, 256, 0, stream>>>(x, xb);
        k_bg<4, 2, false><<<dim3(250, 4), 512, 0, stream>>>(xb, D_, headt, D_, logits, V_, head_b, D_);
        return;
    }

    // ---- fallback: R5 fp32-operand path (verified passing) ----
    float* ws = (float*)d_ws;
    float* x2 = ws;
    float* xn2 = x2 + 1048576;
    float* qkv2p = xn2 + 1048576;
    float* ctx2 = qkv2p + 3145728;
    float* attn2 = ctx2 + 1048576;
    float *hbuf, *gbuf2, *abuf;
    size_t need = (size_t)23068672 * sizeof(float);
    if (ws_size >= need) {
        hbuf = attn2 + 1048576;
        gbuf2 = hbuf + 4194304;
        abuf = gbuf2 + 8388608;
    } else {
        hbuf = logits;
        gbuf2 = hbuf + 4194304;
        abuf = gbuf2 + 8388608;
    }
    k_embed<<<1024, 256, 0, stream>>>(tokens, embed, x2);
    for (int l = 0; l < L_; l++) {
        for (int a = 0; a < 2; a++) {
            const float* lns = (a == 0 ? ln1_s : ln2_s) + (long)l * D_;
            const float* lnb = (a == 0 ? ln1_b : ln2_b) + (long)l * D_;
            const float* Wq = (a == 0 ? qkv1_w : qkv2_w) + (long)l * D_ * 3 * D_;
            const float* bq = (a == 0 ? qkv1_b : qkv2_b) + (long)l * 3 * D_;
            const float* Wo = (a == 0 ? out1_w : out2_w) + (long)l * D_ * D_;
            const float* bo = (a == 0 ? out1_b : out2_b) + (long)l * D_;
            float* wmap = (a == 0 ? att1 : att2) + (long)l * H_ * S_ * S_;
            k_ln<<<S_, 256, 0, stream>>>(x2, lns, lnb, xn2, nullptr);
            k_bgemm<<<dim3(24, 8), 256, 0, stream>>>(xn2, D_, Wq, 3 * D_, qkv2p, 3 * D_, bq, D_);
            k_scores<<<dim3(16, 16, 16), 256, 0, stream>>>(qkv2p, wmap);
            k_softmax<<<H_ * S_, 256, 0, stream>>>(wmap);
            k_pv<<<dim3(16, 16), 256, 0, stream>>>(wmap, qkv2p, ctx2, nullptr);
            k_bgemm<<<dim3(8, 8), 256, 0, stream>>>(ctx2, D_, Wo, D_, attn2, D_, bo, D_);
            k_add<<<1024, 256, 0, stream>>>(x2, xn2, attn2);
        }
        k_ln<<<S_, 256, 0, stream>>>(x2, ln3_s + (long)l * D_, ln3_b + (long)l * D_, xn2, nullptr);
        k_bgemm<<<dim3(32, 8), 256, 0, stream>>>(xn2, D_, ffn1_w + (long)l * D_ * F_, F_,
                                                 hbuf, F_, ffn1_b + (long)l * F_, D_);
        k_bgemm<<<dim3(64, 8), 256, 0, stream>>>(hbuf, F_, ffng_w + (long)l * F_ * 2 * F_, 2 * F_,
                                                 gbuf2, 2 * F_, ffng_b + (long)l * 2 * F_, F_);
        k_geglu<<<4096, 256, 0, stream>>>(gbuf2, abuf, nullptr);
        k_bgemm<<<dim3(8, 8), 256, 0, stream>>>(abuf, F_, ffn2_w + (long)l * F_ * D_, D_,
                                                hbuf, D_, ffn2_b + (long)l * D_, F_);
        k_add<<<1024, 256, 0, stream>>>(x2, hbuf, attn2);
    }
    k_bgemm<<<dim3(250, 8), 256, 0, stream>>>(x2, D_, head_w, V_, logits, V_, head_b, D_);
}